// Round 2
// baseline (1092.284 us; speedup 1.0000x reference)
//
#include <hip/hip_runtime.h>
#include <cstdint>
#include <cstddef>

// Dropout mask variant (JAX threefry semantics):
//  0: partitionable counter (0,i), take LOW output word   [round 1: FAILED, absmax 7.4]
//  1: partitionable counter (0,i), take HIGH output word
//  2: legacy non-partitionable mode (iota split in halves, outputs concatenated)
//  3: partitionable counter (0,i), XOR of both output words  <-- this round
#define DROPOUT_VARIANT 3

// ---------------- Threefry-2x32-20, key (0,42) ----------------
static __device__ __forceinline__ uint32_t rotl32(uint32_t v, int d) {
  return (v << d) | (v >> (32 - d));
}

static __device__ __forceinline__ void threefry2x32(uint32_t k0, uint32_t k1,
                                                    uint32_t& x0, uint32_t& x1) {
  uint32_t k2 = k0 ^ k1 ^ 0x1BD11BDAu;
  x0 += k0; x1 += k1;
#define TF_R(r) { x0 += x1; x1 = rotl32(x1, (r)); x1 ^= x0; }
  TF_R(13) TF_R(15) TF_R(26) TF_R(6)
  x0 += k1; x1 += k2 + 1u;
  TF_R(17) TF_R(29) TF_R(16) TF_R(24)
  x0 += k2; x1 += k0 + 2u;
  TF_R(13) TF_R(15) TF_R(26) TF_R(6)
  x0 += k0; x1 += k1 + 3u;
  TF_R(17) TF_R(29) TF_R(16) TF_R(24)
  x0 += k1; x1 += k2 + 4u;
  TF_R(13) TF_R(15) TF_R(26) TF_R(6)
  x0 += k2; x1 += k0 + 5u;
#undef TF_R
}

// ---------------- graph preprocessing ----------------
__global__ void init_kernel(int* cnt, int* cursor, int n) {
  int i = blockIdx.x * blockDim.x + threadIdx.x;
  if (i < n) { cnt[i] = 0; cursor[i] = 0; }
}

__global__ void count_kernel(const int* __restrict__ fd, int* __restrict__ cnt, int e) {
  int i = blockIdx.x * blockDim.x + threadIdx.x;
  if (i < e) atomicAdd(&cnt[fd[i]], 1);
}

// exclusive scan of cnt -> off, per-block partials
__global__ void scanA_kernel(const int* __restrict__ cnt, int* __restrict__ off,
                             int* __restrict__ bsum, int n) {
  __shared__ int s[256];
  int t = threadIdx.x;
  int i = blockIdx.x * 256 + t;
  int v = (i < n) ? cnt[i] : 0;
  s[t] = v;
  __syncthreads();
  for (int d = 1; d < 256; d <<= 1) {
    int add = (t >= d) ? s[t - d] : 0;
    __syncthreads();
    s[t] += add;
    __syncthreads();
  }
  if (i < n) off[i] = s[t] - v;  // exclusive
  if (t == 255) bsum[blockIdx.x] = s[255];
}

__global__ void scanB_kernel(const int* __restrict__ bsum, int* __restrict__ boff,
                             int nb, int* __restrict__ off, int n) {
  __shared__ int s[512];
  int t = threadIdx.x;
  int v = (t < nb) ? bsum[t] : 0;
  s[t] = v;
  __syncthreads();
  for (int d = 1; d < 512; d <<= 1) {
    int add = (t >= d) ? s[t - d] : 0;
    __syncthreads();
    s[t] += add;
    __syncthreads();
  }
  if (t < nb) boff[t] = s[t] - v;
  if (t == nb - 1) off[n] = s[t];  // total = E
}

__global__ void scanC_kernel(int* __restrict__ off, const int* __restrict__ boff,
                             const int* __restrict__ cnt, float* __restrict__ dis, int n) {
  int i = blockIdx.x * 256 + threadIdx.x;
  if (i < n) {
    off[i] += boff[blockIdx.x];
    dis[i] = 1.0f / sqrtf((float)(cnt[i] + 1));  // deg includes self-loop
  }
}

__global__ void fill_kernel(const int* __restrict__ fs, const int* __restrict__ fd,
                            const int* __restrict__ off, int* __restrict__ cursor,
                            const float* __restrict__ dis,
                            int* __restrict__ csr_src, float* __restrict__ csr_w, int e) {
  int i = blockIdx.x * blockDim.x + threadIdx.x;
  if (i < e) {
    int s = fs[i], d = fd[i];
    int pos = atomicAdd(&cursor[d], 1);
    int slot = off[d] + pos;
    csr_src[slot] = s;
    csr_w[slot] = dis[s] * dis[d];
  }
}

// h = query[batch] * x   (per float4)
__global__ void h0_kernel(const float* __restrict__ x, const float* __restrict__ query,
                          const int* __restrict__ batch, float* __restrict__ h, int n) {
  int i = blockIdx.x * blockDim.x + threadIdx.x;
  int total = n * 32;  // 32 float4 per 128-wide row
  if (i < total) {
    int node = i >> 5;
    int q = i & 31;
    int b = batch[node];
    float4 xv = ((const float4*)x)[i];
    float4 qv = ((const float4*)query)[b * 32 + q];
    float4 r = make_float4(xv.x * qv.x, xv.y * qv.y, xv.z * qv.z, xv.w * qv.w);
    ((float4*)h)[i] = r;
  }
}

// ---------------- fp32 tiled GEMM: C[nrows,BN] = A[nrows,128] @ W[128,BN] (+bias) ----------------
template<int BN, int TN>
__global__ __launch_bounds__(256)
void gemm_kernel(const float* __restrict__ A, const float* __restrict__ Wm,
                 const float* __restrict__ bias, float* __restrict__ C, int nrows) {
  __shared__ float As[32][132];   // transposed A tile: As[k][m], padded
  __shared__ float Bs[32][BN];
  const int tid = threadIdx.x;
  const int tr = tid >> 4;   // 0..15 -> rows tr*8..tr*8+7
  const int tc = tid & 15;   // 0..15 -> cols tc*TN..
  const int rowbase = blockIdx.x * 128;
  float acc[8][TN];
#pragma unroll
  for (int i = 0; i < 8; ++i)
#pragma unroll
    for (int j = 0; j < TN; ++j) acc[i][j] = 0.f;

  for (int k0 = 0; k0 < 128; k0 += 32) {
    // stage A tile (128 rows x 32 k), transposed into As[k][m]
#pragma unroll
    for (int l = 0; l < 4; ++l) {
      int q = tid + l * 256;       // 0..1023
      int row = q >> 3;            // 0..127
      int kq = q & 7;              // 8 float4 per row
      int gr = rowbase + row;
      float4 v = make_float4(0.f, 0.f, 0.f, 0.f);
      if (gr < nrows) v = *(const float4*)(A + (size_t)gr * 128 + k0 + kq * 4);
      As[kq * 4 + 0][row] = v.x;
      As[kq * 4 + 1][row] = v.y;
      As[kq * 4 + 2][row] = v.z;
      As[kq * 4 + 3][row] = v.w;
    }
    // stage W tile (32 k x BN)
#pragma unroll
    for (int l = 0; l < (32 * BN / 4) / 256; ++l) {
      int q = tid + l * 256;
      int k = q / (BN / 4);
      int cq = q % (BN / 4);
      float4 v = *(const float4*)(Wm + (size_t)(k0 + k) * BN + cq * 4);
      *(float4*)(&Bs[k][cq * 4]) = v;
    }
    __syncthreads();
#pragma unroll
    for (int k = 0; k < 32; ++k) {
      float a[8], b[TN];
      *(float4*)(&a[0]) = *(const float4*)(&As[k][tr * 8]);
      *(float4*)(&a[4]) = *(const float4*)(&As[k][tr * 8 + 4]);
      *(float4*)(&b[0]) = *(const float4*)(&Bs[k][tc * TN]);
      if constexpr (TN == 8) {
        *(float4*)(&b[4]) = *(const float4*)(&Bs[k][tc * TN + 4]);
      }
#pragma unroll
      for (int i = 0; i < 8; ++i)
#pragma unroll
        for (int j = 0; j < TN; ++j)
          acc[i][j] = fmaf(a[i], b[j], acc[i][j]);
    }
    __syncthreads();
  }
#pragma unroll
  for (int i = 0; i < 8; ++i) {
    int gr = rowbase + tr * 8 + i;
    if (gr < nrows) {
#pragma unroll
      for (int j = 0; j < TN; j += 4) {
        float4 o = make_float4(acc[i][j], acc[i][j + 1], acc[i][j + 2], acc[i][j + 3]);
        if (bias) {
          o.x += bias[tc * TN + j + 0];
          o.y += bias[tc * TN + j + 1];
          o.z += bias[tc * TN + j + 2];
          o.w += bias[tc * TN + j + 3];
        }
        *(float4*)(C + (size_t)gr * BN + tc * TN + j) = o;
      }
    }
  }
}

// ---------------- aggregation: one wave64 per node ----------------
// h[v] := maybe_relu( bias + h[v](res) + dis[v]^2*hw[v] + sum_edges w*hw[src] )
__global__ __launch_bounds__(256)
void agg_kernel(const float* __restrict__ hw, float* __restrict__ h,
                const float* __restrict__ bias, const int* __restrict__ off,
                const int* __restrict__ csr_src, const float* __restrict__ csr_w,
                const float* __restrict__ dis, int relu, int n) {
  int wid = (blockIdx.x * blockDim.x + threadIdx.x) >> 6;
  int lane = threadIdx.x & 63;
  if (wid >= n) return;
  int v = wid;
  float dv = dis[v];
  float sw = dv * dv;
  float2 hv = ((const float2*)(hw + (size_t)v * 128))[lane];
  float2* hr = (float2*)(h + (size_t)v * 128);
  float2 res = hr[lane];
  float2 bb = ((const float2*)bias)[lane];
  float accx = bb.x + res.x + sw * hv.x;
  float accy = bb.y + res.y + sw * hv.y;
  int s0 = off[v], s1 = off[v + 1];
  for (int i = s0; i < s1; ++i) {
    int s = csr_src[i];
    float w = csr_w[i];
    float2 t = ((const float2*)(hw + (size_t)s * 128))[lane];
    accx = fmaf(w, t.x, accx);
    accy = fmaf(w, t.y, accy);
  }
  if (relu) { accx = fmaxf(accx, 0.f); accy = fmaxf(accy, 0.f); }
  hr[lane] = make_float2(accx, accy);
}

// ---------------- dropout (bit-exact JAX threefry) ----------------
// mode: 0 = low word, 1 = high word, 3 = xor of words; counter = (0, i)
__global__ void dropout_part_kernel(float* __restrict__ out, int total, int mode) {
  int i = blockIdx.x * blockDim.x + threadIdx.x;
  if (i >= total) return;
  uint32_t x0 = 0u, x1 = (uint32_t)i;   // counter = (hi,lo) of u64 flat index
  threefry2x32(0u, 42u, x0, x1);
  uint32_t bits = (mode == 1) ? x0 : ((mode == 3) ? (x0 ^ x1) : x1);
  float u = __uint_as_float((bits >> 9) | 0x3F800000u) - 1.0f;
  float v = out[i];
  out[i] = (u < 0.8f) ? (v / 0.8f) : 0.0f;
}

__global__ void dropout_orig_kernel(float* __restrict__ out, int half) {
  int i = blockIdx.x * blockDim.x + threadIdx.x;
  if (i >= half) return;
  uint32_t x0 = (uint32_t)i, x1 = (uint32_t)(i + half);
  threefry2x32(0u, 42u, x0, x1);
  float u0 = __uint_as_float((x0 >> 9) | 0x3F800000u) - 1.0f;
  float u1 = __uint_as_float((x1 >> 9) | 0x3F800000u) - 1.0f;
  float a = out[i], b = out[i + half];
  out[i] = (u0 < 0.8f) ? (a / 0.8f) : 0.0f;
  out[i + half] = (u1 < 0.8f) ? (b / 0.8f) : 0.0f;
}

// ---------------- launch ----------------
extern "C" void kernel_launch(void* const* d_in, const int* in_sizes, int n_in,
                              void* d_out, int out_size, void* d_ws, size_t ws_size,
                              hipStream_t stream) {
  const float* x     = (const float*)d_in[0];
  const float* query = (const float*)d_in[1];
  const int*   batch = (const int*)d_in[2];
  const int*   eidx  = (const int*)d_in[3];
  const float* W[4]  = {(const float*)d_in[4], (const float*)d_in[6],
                        (const float*)d_in[8], (const float*)d_in[10]};
  const float* bv[4] = {(const float*)d_in[5], (const float*)d_in[7],
                        (const float*)d_in[9], (const float*)d_in[11]};
  const float* Wc = (const float*)d_in[12];
  const float* bc = (const float*)d_in[13];
  float* out = (float*)d_out;

  const int n = in_sizes[2];       // 100000
  const int e = in_sizes[3] / 2;   // 1600000
  const int* fs = eidx;            // edge_index[0] = sources
  const int* fd = eidx + e;        // edge_index[1] = targets (aggregation index)

  // workspace carve (~117 MB total)
  char* p = (char*)d_ws;
  auto carve = [&](size_t bytes) -> void* {
    void* r = (void*)p;
    p += (bytes + 255) & ~(size_t)255;
    return r;
  };
  const int nscan = (n + 255) / 256;           // 391 (must be <= 512 for scanB)
  int*   cnt     = (int*)carve((size_t)n * 4);
  int*   cursor  = (int*)carve((size_t)n * 4);
  int*   off     = (int*)carve((size_t)(n + 1) * 4);
  int*   bsum    = (int*)carve((size_t)nscan * 4);
  int*   boff    = (int*)carve((size_t)nscan * 4);
  float* dis     = (float*)carve((size_t)n * 4);
  int*   csr_src = (int*)carve((size_t)e * 4);
  float* csr_w   = (float*)carve((size_t)e * 4);
  float* h       = (float*)carve((size_t)n * 128 * 4);
  float* hw      = (float*)carve((size_t)n * 128 * 4);

  const int eb = (e + 255) / 256;

  init_kernel<<<nscan, 256, 0, stream>>>(cnt, cursor, n);
  count_kernel<<<eb, 256, 0, stream>>>(fd, cnt, e);
  scanA_kernel<<<nscan, 256, 0, stream>>>(cnt, off, bsum, n);
  scanB_kernel<<<1, 512, 0, stream>>>(bsum, boff, nscan, off, n);
  scanC_kernel<<<nscan, 256, 0, stream>>>(off, boff, cnt, dis, n);
  fill_kernel<<<eb, 256, 0, stream>>>(fs, fd, off, cursor, dis, csr_src, csr_w, e);
  h0_kernel<<<(n * 32 + 255) / 256, 256, 0, stream>>>(x, query, batch, h, n);

  const int gblk = (n + 127) / 128;
  for (int l = 0; l < 4; ++l) {
    gemm_kernel<128, 8><<<gblk, 256, 0, stream>>>(h, W[l], nullptr, hw, n);
    agg_kernel<<<(n + 3) / 4, 256, 0, stream>>>(hw, h, bv[l], off, csr_src, csr_w,
                                                dis, (l < 3) ? 1 : 0, n);
  }
  gemm_kernel<64, 4><<<gblk, 256, 0, stream>>>(h, Wc, bc, out, n);

  const int total = n * 64;
#if DROPOUT_VARIANT == 2
  dropout_orig_kernel<<<((total / 2) + 255) / 256, 256, 0, stream>>>(out, total / 2);
#else
  dropout_part_kernel<<<(total + 255) / 256, 256, 0, stream>>>(out, total,
                                                               DROPOUT_VARIANT);
#endif
}

// Round 3
// 876.916 us; speedup vs baseline: 1.2456x; 1.2456x over previous
//
#include <hip/hip_runtime.h>
#include <cstdint>
#include <cstddef>

#define DROPOUT_VARIANT 3  // partitionable counter (0,i), XOR of output words [verified round 2]

// ---------------- bf16 helpers ----------------
static __device__ __forceinline__ uint32_t f2bf(float x) {
  uint32_t u = __float_as_uint(x);
  return (u + 0x7fffu + ((u >> 16) & 1u)) >> 16;  // RNE
}
static __device__ __forceinline__ uint32_t pack2(float a, float b) {
  return f2bf(a) | (f2bf(b) << 16);
}
static __device__ __forceinline__ float bf_lo(uint32_t u) { return __uint_as_float(u << 16); }
static __device__ __forceinline__ float bf_hi(uint32_t u) { return __uint_as_float(u & 0xffff0000u); }

// ---------------- Threefry-2x32-20, key (0,42) ----------------
static __device__ __forceinline__ uint32_t rotl32(uint32_t v, int d) {
  return (v << d) | (v >> (32 - d));
}

static __device__ __forceinline__ void threefry2x32(uint32_t k0, uint32_t k1,
                                                    uint32_t& x0, uint32_t& x1) {
  uint32_t k2 = k0 ^ k1 ^ 0x1BD11BDAu;
  x0 += k0; x1 += k1;
#define TF_R(r) { x0 += x1; x1 = rotl32(x1, (r)); x1 ^= x0; }
  TF_R(13) TF_R(15) TF_R(26) TF_R(6)
  x0 += k1; x1 += k2 + 1u;
  TF_R(17) TF_R(29) TF_R(16) TF_R(24)
  x0 += k2; x1 += k0 + 2u;
  TF_R(13) TF_R(15) TF_R(26) TF_R(6)
  x0 += k0; x1 += k1 + 3u;
  TF_R(17) TF_R(29) TF_R(16) TF_R(24)
  x0 += k1; x1 += k2 + 4u;
  TF_R(13) TF_R(15) TF_R(26) TF_R(6)
  x0 += k2; x1 += k0 + 5u;
#undef TF_R
}

// ---------------- graph preprocessing ----------------
__global__ void init_kernel(int* cnt, int* cursor, int n) {
  int i = blockIdx.x * blockDim.x + threadIdx.x;
  if (i < n) { cnt[i] = 0; cursor[i] = 0; }
}

__global__ void count_kernel(const int* __restrict__ fd, int* __restrict__ cnt, int e) {
  int i = blockIdx.x * blockDim.x + threadIdx.x;
  if (i < e) atomicAdd(&cnt[fd[i]], 1);
}

__global__ void scanA_kernel(const int* __restrict__ cnt, int* __restrict__ off,
                             int* __restrict__ bsum, int n) {
  __shared__ int s[256];
  int t = threadIdx.x;
  int i = blockIdx.x * 256 + t;
  int v = (i < n) ? cnt[i] : 0;
  s[t] = v;
  __syncthreads();
  for (int d = 1; d < 256; d <<= 1) {
    int add = (t >= d) ? s[t - d] : 0;
    __syncthreads();
    s[t] += add;
    __syncthreads();
  }
  if (i < n) off[i] = s[t] - v;  // exclusive
  if (t == 255) bsum[blockIdx.x] = s[255];
}

__global__ void scanB_kernel(const int* __restrict__ bsum, int* __restrict__ boff,
                             int nb, int* __restrict__ off, int n) {
  __shared__ int s[512];
  int t = threadIdx.x;
  int v = (t < nb) ? bsum[t] : 0;
  s[t] = v;
  __syncthreads();
  for (int d = 1; d < 512; d <<= 1) {
    int add = (t >= d) ? s[t - d] : 0;
    __syncthreads();
    s[t] += add;
    __syncthreads();
  }
  if (t < nb) boff[t] = s[t] - v;
  if (t == nb - 1) off[n] = s[t];  // total = E
}

__global__ void scanC_kernel(int* __restrict__ off, const int* __restrict__ boff,
                             const int* __restrict__ cnt, float* __restrict__ dis, int n) {
  int i = blockIdx.x * 256 + threadIdx.x;
  if (i < n) {
    off[i] += boff[blockIdx.x];
    dis[i] = 1.0f / sqrtf((float)(cnt[i] + 1));  // deg includes self-loop
  }
}

__global__ void fill_kernel(const int* __restrict__ fs, const int* __restrict__ fd,
                            const int* __restrict__ off, int* __restrict__ cursor,
                            const float* __restrict__ dis,
                            int* __restrict__ csr_src, float* __restrict__ csr_w, int e) {
  int i = blockIdx.x * blockDim.x + threadIdx.x;
  if (i < e) {
    int s = fs[i], d = fd[i];
    int pos = atomicAdd(&cursor[d], 1);
    int slot = off[d] + pos;
    csr_src[slot] = s;
    csr_w[slot] = dis[s] * dis[d];
  }
}

// h = query[batch] * x : write fp32 h (residual path) + bf16 hb (GEMM input)
__global__ void h0_kernel(const float* __restrict__ x, const float* __restrict__ query,
                          const int* __restrict__ batch, float* __restrict__ h,
                          uint32_t* __restrict__ hb, int n) {
  int i = blockIdx.x * blockDim.x + threadIdx.x;  // one bf16x2 word (2 cols)
  int total = n * 64;
  if (i < total) {
    int node = i >> 6;
    int w = i & 63;
    int b = batch[node];
    float2 xv = ((const float2*)x)[i];
    float2 qv = ((const float2*)query)[b * 64 + w];
    float2 r = make_float2(xv.x * qv.x, xv.y * qv.y);
    ((float2*)h)[i] = r;
    hb[i] = pack2(r.x, r.y);
  }
}

// ---------------- tiled GEMM: C[nrows,BN] = A_bf16[nrows,128] @ W_f32[128,BN] (+bias) ----------------
// A is bf16 (exactly what the previous stage quantized); compute fp32 FMA; output bf16 or fp32.
template<int BN, int TN, int OUT_BF16>
__global__ __launch_bounds__(256)
void gemm_kernel(const uint32_t* __restrict__ Abf,  // bf16x2 words, row stride 64
                 const float* __restrict__ Wm, const float* __restrict__ bias,
                 void* __restrict__ Cout, int nrows) {
  __shared__ float As[32][132];   // transposed A tile: As[k][m], padded
  __shared__ float Bs[32][BN];
  const int tid = threadIdx.x;
  const int tr = tid >> 4;   // 0..15 -> rows tr*8..tr*8+7
  const int tc = tid & 15;   // 0..15 -> cols tc*TN..
  const int rowbase = blockIdx.x * 128;
  float acc[8][TN];
#pragma unroll
  for (int i = 0; i < 8; ++i)
#pragma unroll
    for (int j = 0; j < TN; ++j) acc[i][j] = 0.f;

  for (int k0 = 0; k0 < 128; k0 += 32) {
    // stage A tile (128 rows x 32 k bf16), transposed into As[k][m]
#pragma unroll
    for (int l = 0; l < 2; ++l) {
      int q = tid + l * 256;       // 0..511
      int row = q >> 2;            // 0..127
      int kq = q & 3;              // 4 uint4 (8 bf16) groups per row
      int gr = rowbase + row;
      uint4 v = make_uint4(0u, 0u, 0u, 0u);
      if (gr < nrows) v = *(const uint4*)(Abf + (size_t)gr * 64 + (k0 >> 1) + kq * 4);
      int kb = kq * 8;
      As[kb + 0][row] = bf_lo(v.x); As[kb + 1][row] = bf_hi(v.x);
      As[kb + 2][row] = bf_lo(v.y); As[kb + 3][row] = bf_hi(v.y);
      As[kb + 4][row] = bf_lo(v.z); As[kb + 5][row] = bf_hi(v.z);
      As[kb + 6][row] = bf_lo(v.w); As[kb + 7][row] = bf_hi(v.w);
    }
    // stage W tile (32 k x BN)
#pragma unroll
    for (int l = 0; l < (32 * BN / 4) / 256; ++l) {
      int q = tid + l * 256;
      int k = q / (BN / 4);
      int cq = q % (BN / 4);
      float4 v = *(const float4*)(Wm + (size_t)(k0 + k) * BN + cq * 4);
      *(float4*)(&Bs[k][cq * 4]) = v;
    }
    __syncthreads();
#pragma unroll
    for (int k = 0; k < 32; ++k) {
      float a[8], b[TN];
      *(float4*)(&a[0]) = *(const float4*)(&As[k][tr * 8]);
      *(float4*)(&a[4]) = *(const float4*)(&As[k][tr * 8 + 4]);
      *(float4*)(&b[0]) = *(const float4*)(&Bs[k][tc * TN]);
      if constexpr (TN == 8) {
        *(float4*)(&b[4]) = *(const float4*)(&Bs[k][tc * TN + 4]);
      }
#pragma unroll
      for (int i = 0; i < 8; ++i)
#pragma unroll
        for (int j = 0; j < TN; ++j)
          acc[i][j] = fmaf(a[i], b[j], acc[i][j]);
    }
    __syncthreads();
  }
#pragma unroll
  for (int i = 0; i < 8; ++i) {
    int gr = rowbase + tr * 8 + i;
    if (gr < nrows) {
      if constexpr (OUT_BF16) {
        // pack TN=8 floats -> 4 bf16x2 words, one uint4 store
        uint32_t* C = (uint32_t*)Cout;
        uint4 o;
        o.x = pack2(acc[i][0], acc[i][1]);
        o.y = pack2(acc[i][2], acc[i][3]);
        o.z = pack2(acc[i][4], acc[i][5]);
        o.w = pack2(acc[i][6], acc[i][7]);
        *(uint4*)(C + (size_t)gr * (BN / 2) + tc * (TN / 2)) = o;
      } else {
        float* C = (float*)Cout;
#pragma unroll
        for (int j = 0; j < TN; j += 4) {
          float4 o = make_float4(acc[i][j], acc[i][j + 1], acc[i][j + 2], acc[i][j + 3]);
          if (bias) {
            o.x += bias[tc * TN + j + 0];
            o.y += bias[tc * TN + j + 1];
            o.z += bias[tc * TN + j + 2];
            o.w += bias[tc * TN + j + 3];
          }
          *(float4*)(C + (size_t)gr * BN + tc * TN + j) = o;
        }
      }
    }
  }
}

// ---------------- aggregation: one wave64 per node, bf16 rows ----------------
// h[v] := maybe_relu( bias + h[v](res) + dis[v]^2*hw[v] + sum_edges w*hw[src] )
// also writes hb (bf16 copy of new h) for the next GEMM's input.
__global__ __launch_bounds__(256)
void agg_kernel(const uint32_t* __restrict__ hwb, float* __restrict__ h,
                uint32_t* __restrict__ hb, const float* __restrict__ bias,
                const int* __restrict__ off, const int* __restrict__ csr_src,
                const float* __restrict__ csr_w, const float* __restrict__ dis,
                int relu, int n) {
  int wid = (blockIdx.x * blockDim.x + threadIdx.x) >> 6;
  int lane = threadIdx.x & 63;
  if (wid >= n) return;
  int v = wid;
  float dv = dis[v];
  float sw = dv * dv;
  uint32_t hvw = hwb[(size_t)v * 64 + lane];
  float2* hr = (float2*)(h + (size_t)v * 128);
  float2 res = hr[lane];
  float2 bb = ((const float2*)bias)[lane];
  float accx = fmaf(sw, bf_lo(hvw), bb.x + res.x);
  float accy = fmaf(sw, bf_hi(hvw), bb.y + res.y);
  int s0 = off[v], s1 = off[v + 1];
  int i = s0;
  for (; i + 1 < s1; i += 2) {   // 2-way unroll for memory-level parallelism
    int sa = csr_src[i], sb = csr_src[i + 1];
    float wa = csr_w[i], wb = csr_w[i + 1];
    uint32_t ra = hwb[(size_t)sa * 64 + lane];
    uint32_t rb = hwb[(size_t)sb * 64 + lane];
    accx = fmaf(wa, bf_lo(ra), accx);
    accy = fmaf(wa, bf_hi(ra), accy);
    accx = fmaf(wb, bf_lo(rb), accx);
    accy = fmaf(wb, bf_hi(rb), accy);
  }
  if (i < s1) {
    int sa = csr_src[i];
    float wa = csr_w[i];
    uint32_t ra = hwb[(size_t)sa * 64 + lane];
    accx = fmaf(wa, bf_lo(ra), accx);
    accy = fmaf(wa, bf_hi(ra), accy);
  }
  if (relu) { accx = fmaxf(accx, 0.f); accy = fmaxf(accy, 0.f); }
  hr[lane] = make_float2(accx, accy);
  hb[(size_t)v * 64 + lane] = pack2(accx, accy);
}

// ---------------- dropout (bit-exact JAX threefry) ----------------
__global__ void dropout_part_kernel(float* __restrict__ out, int total, int mode) {
  int i = blockIdx.x * blockDim.x + threadIdx.x;
  if (i >= total) return;
  uint32_t x0 = 0u, x1 = (uint32_t)i;   // counter = (hi,lo) of u64 flat index
  threefry2x32(0u, 42u, x0, x1);
  uint32_t bits = (mode == 1) ? x0 : ((mode == 3) ? (x0 ^ x1) : x1);
  float u = __uint_as_float((bits >> 9) | 0x3F800000u) - 1.0f;
  float v = out[i];
  out[i] = (u < 0.8f) ? (v / 0.8f) : 0.0f;
}

// ---------------- launch ----------------
extern "C" void kernel_launch(void* const* d_in, const int* in_sizes, int n_in,
                              void* d_out, int out_size, void* d_ws, size_t ws_size,
                              hipStream_t stream) {
  const float* x     = (const float*)d_in[0];
  const float* query = (const float*)d_in[1];
  const int*   batch = (const int*)d_in[2];
  const int*   eidx  = (const int*)d_in[3];
  const float* W[4]  = {(const float*)d_in[4], (const float*)d_in[6],
                        (const float*)d_in[8], (const float*)d_in[10]};
  const float* bv[4] = {(const float*)d_in[5], (const float*)d_in[7],
                        (const float*)d_in[9], (const float*)d_in[11]};
  const float* Wc = (const float*)d_in[12];
  const float* bc = (const float*)d_in[13];
  float* out = (float*)d_out;

  const int n = in_sizes[2];       // 100000
  const int e = in_sizes[3] / 2;   // 1600000
  const int* fs = eidx;            // edge_index[0] = sources
  const int* fd = eidx + e;        // edge_index[1] = targets (aggregation index)

  char* p = (char*)d_ws;
  auto carve = [&](size_t bytes) -> void* {
    void* r = (void*)p;
    p += (bytes + 255) & ~(size_t)255;
    return r;
  };
  const int nscan = (n + 255) / 256;           // 391 (<= 512 for scanB)
  int*      cnt     = (int*)carve((size_t)n * 4);
  int*      cursor  = (int*)carve((size_t)n * 4);
  int*      off     = (int*)carve((size_t)(n + 1) * 4);
  int*      bsum    = (int*)carve((size_t)nscan * 4);
  int*      boff    = (int*)carve((size_t)nscan * 4);
  float*    dis     = (float*)carve((size_t)n * 4);
  int*      csr_src = (int*)carve((size_t)e * 4);
  float*    csr_w   = (float*)carve((size_t)e * 4);
  float*    h       = (float*)carve((size_t)n * 128 * 4);   // fp32 residual
  uint32_t* hb      = (uint32_t*)carve((size_t)n * 64 * 4); // bf16 h (GEMM input)
  uint32_t* hwb     = (uint32_t*)carve((size_t)n * 64 * 4); // bf16 h@W (gather src)

  const int eb = (e + 255) / 256;

  init_kernel<<<nscan, 256, 0, stream>>>(cnt, cursor, n);
  count_kernel<<<eb, 256, 0, stream>>>(fd, cnt, e);
  scanA_kernel<<<nscan, 256, 0, stream>>>(cnt, off, bsum, n);
  scanB_kernel<<<1, 512, 0, stream>>>(bsum, boff, nscan, off, n);
  scanC_kernel<<<nscan, 256, 0, stream>>>(off, boff, cnt, dis, n);
  fill_kernel<<<eb, 256, 0, stream>>>(fs, fd, off, cursor, dis, csr_src, csr_w, e);
  h0_kernel<<<(n * 64 + 255) / 256, 256, 0, stream>>>(x, query, batch, h, hb, n);

  const int gblk = (n + 127) / 128;
  for (int l = 0; l < 4; ++l) {
    gemm_kernel<128, 8, 1><<<gblk, 256, 0, stream>>>(hb, W[l], nullptr, hwb, n);
    agg_kernel<<<(n + 3) / 4, 256, 0, stream>>>(hwb, h, hb, bv[l], off, csr_src,
                                                csr_w, dis, (l < 3) ? 1 : 0, n);
  }
  gemm_kernel<64, 4, 0><<<gblk, 256, 0, stream>>>(hb, Wc, bc, out, n);

  const int total = n * 64;
  dropout_part_kernel<<<(total + 255) / 256, 256, 0, stream>>>(out, total,
                                                               DROPOUT_VARIANT);
}

// Round 4
// 716.679 us; speedup vs baseline: 1.5241x; 1.2236x over previous
//
#include <hip/hip_runtime.h>
#include <cstdint>
#include <cstddef>

#define DROPOUT_VARIANT 3  // partitionable counter (0,i), XOR of output words [verified round 2]

typedef short bf16x8 __attribute__((ext_vector_type(8)));
typedef float f32x4 __attribute__((ext_vector_type(4)));

// ---------------- bf16 helpers ----------------
static __device__ __forceinline__ uint32_t f2bf(float x) {
  uint32_t u = __float_as_uint(x);
  return (u + 0x7fffu + ((u >> 16) & 1u)) >> 16;  // RNE
}
static __device__ __forceinline__ uint32_t pack2(float a, float b) {
  return f2bf(a) | (f2bf(b) << 16);
}
static __device__ __forceinline__ float bf_lo(uint32_t u) { return __uint_as_float(u << 16); }
static __device__ __forceinline__ float bf_hi(uint32_t u) { return __uint_as_float(u & 0xffff0000u); }

// ---------------- Threefry-2x32-20, key (0,42) ----------------
static __device__ __forceinline__ uint32_t rotl32(uint32_t v, int d) {
  return (v << d) | (v >> (32 - d));
}

static __device__ __forceinline__ void threefry2x32(uint32_t k0, uint32_t k1,
                                                    uint32_t& x0, uint32_t& x1) {
  uint32_t k2 = k0 ^ k1 ^ 0x1BD11BDAu;
  x0 += k0; x1 += k1;
#define TF_R(r) { x0 += x1; x1 = rotl32(x1, (r)); x1 ^= x0; }
  TF_R(13) TF_R(15) TF_R(26) TF_R(6)
  x0 += k1; x1 += k2 + 1u;
  TF_R(17) TF_R(29) TF_R(16) TF_R(24)
  x0 += k2; x1 += k0 + 2u;
  TF_R(13) TF_R(15) TF_R(26) TF_R(6)
  x0 += k0; x1 += k1 + 3u;
  TF_R(17) TF_R(29) TF_R(16) TF_R(24)
  x0 += k1; x1 += k2 + 4u;
  TF_R(13) TF_R(15) TF_R(26) TF_R(6)
  x0 += k2; x1 += k0 + 5u;
#undef TF_R
}

// ---------------- graph preprocessing ----------------
__global__ void init_kernel(int* cnt, int* cursor, int n) {
  int i = blockIdx.x * blockDim.x + threadIdx.x;
  if (i < n) { cnt[i] = 0; cursor[i] = 0; }
}

__global__ void count_kernel(const int* __restrict__ fd, int* __restrict__ cnt, int e) {
  int i = blockIdx.x * blockDim.x + threadIdx.x;
  if (i < e) atomicAdd(&cnt[fd[i]], 1);
}

__global__ void scanA_kernel(const int* __restrict__ cnt, int* __restrict__ off,
                             int* __restrict__ bsum, int n) {
  __shared__ int s[256];
  int t = threadIdx.x;
  int i = blockIdx.x * 256 + t;
  int v = (i < n) ? cnt[i] : 0;
  s[t] = v;
  __syncthreads();
  for (int d = 1; d < 256; d <<= 1) {
    int add = (t >= d) ? s[t - d] : 0;
    __syncthreads();
    s[t] += add;
    __syncthreads();
  }
  if (i < n) off[i] = s[t] - v;  // exclusive
  if (t == 255) bsum[blockIdx.x] = s[255];
}

__global__ void scanB_kernel(const int* __restrict__ bsum, int* __restrict__ boff,
                             int nb, int* __restrict__ off, int n) {
  __shared__ int s[512];
  int t = threadIdx.x;
  int v = (t < nb) ? bsum[t] : 0;
  s[t] = v;
  __syncthreads();
  for (int d = 1; d < 512; d <<= 1) {
    int add = (t >= d) ? s[t - d] : 0;
    __syncthreads();
    s[t] += add;
    __syncthreads();
  }
  if (t < nb) boff[t] = s[t] - v;
  if (t == nb - 1) off[n] = s[t];  // total = E
}

__global__ void scanC_kernel(int* __restrict__ off, const int* __restrict__ boff,
                             const int* __restrict__ cnt, float* __restrict__ dis, int n) {
  int i = blockIdx.x * 256 + threadIdx.x;
  if (i < n) {
    off[i] += boff[blockIdx.x];
    dis[i] = 1.0f / sqrtf((float)(cnt[i] + 1));  // deg includes self-loop
  }
}

// interleaved CSR: one 8B store per edge (halves scattered write-allocate traffic)
__global__ void fill_kernel(const int* __restrict__ fs, const int* __restrict__ fd,
                            const int* __restrict__ off, int* __restrict__ cursor,
                            const float* __restrict__ dis,
                            uint2* __restrict__ csr, int e) {
  int i = blockIdx.x * blockDim.x + threadIdx.x;
  if (i < e) {
    int s = fs[i], d = fd[i];
    int pos = atomicAdd(&cursor[d], 1);
    csr[off[d] + pos] = make_uint2((uint32_t)s, __float_as_uint(dis[s] * dis[d]));
  }
}

// h = query[batch] * x : write fp32 h (residual path) + bf16 hb (GEMM input)
__global__ void h0_kernel(const float* __restrict__ x, const float* __restrict__ query,
                          const int* __restrict__ batch, float* __restrict__ h,
                          uint32_t* __restrict__ hb, int n) {
  int i = blockIdx.x * blockDim.x + threadIdx.x;  // one bf16x2 word (2 cols)
  int total = n * 64;
  if (i < total) {
    int node = i >> 6;
    int w = i & 63;
    int b = batch[node];
    float2 xv = ((const float2*)x)[i];
    float2 qv = ((const float2*)query)[b * 64 + w];
    float2 r = make_float2(xv.x * qv.x, xv.y * qv.y);
    ((float2*)h)[i] = r;
    hb[i] = pack2(r.x, r.y);
  }
}

// ---------------- MFMA GEMM: C[nrows,BN] = A_bf16[nrows,128] @ W_f32[128,BN] ----------------
// W is split into bf16 hi+lo (W = hi + lo) -> two MFMAs per k-step give fp32-grade accuracy.
// Block: 128 rows x BN cols, 4 waves of 32 rows. A-frags loaded directly from global.
template<int BN, int OUT_BF16>
__global__ __launch_bounds__(256)
void mfma_gemm_kernel(const uint32_t* __restrict__ Abf,   // bf16x2 words, row stride 64
                      const float* __restrict__ Wm,       // fp32 [128][BN] row-major
                      const float* __restrict__ bias,     // nullptr or [BN]
                      void* __restrict__ Cout, int nrows) {
  constexpr int CT = BN / 16;                 // col tiles per wave (8 or 4)
  __shared__ short Wt[2][BN][136];            // [hi/lo][col][k] bf16 bits, stride 272B
  const int tid = threadIdx.x;

  // stage W: fp32 row-major [k][col] -> transposed bf16 hi/lo [col][k]
  for (int q = tid; q < (128 * BN) / 4; q += 256) {
    int el = q * 4;
    int k = el / BN;
    int col = el % BN;                        // 4 consecutive cols, same k
    float4 w4 = *(const float4*)(Wm + el);
    float wv[4] = {w4.x, w4.y, w4.z, w4.w};
#pragma unroll
    for (int j = 0; j < 4; ++j) {
      uint32_t hi = f2bf(wv[j]);
      float hif = __uint_as_float(hi << 16);
      uint32_t lo = f2bf(wv[j] - hif);
      Wt[0][col + j][k] = (short)hi;
      Wt[1][col + j][k] = (short)lo;
    }
  }
  __syncthreads();

  const int wave = tid >> 6;
  const int lane = tid & 63;
  const int lrow = lane & 15;                 // A-row / B-col within tile
  const int lk = lane >> 4;                   // k-group (0..3)
  const int rowbase = blockIdx.x * 128 + wave * 32;
  const uint16_t* Au = (const uint16_t*)Abf;

  f32x4 acc[2][CT];
#pragma unroll
  for (int rt = 0; rt < 2; ++rt)
#pragma unroll
    for (int ct = 0; ct < CT; ++ct) acc[rt][ct] = (f32x4){0.f, 0.f, 0.f, 0.f};

#pragma unroll
  for (int s = 0; s < 4; ++s) {               // K-steps of 32
    bf16x8 a[2];
#pragma unroll
    for (int rt = 0; rt < 2; ++rt) {
      int gr = rowbase + rt * 16 + lrow;
      int gra = (gr < nrows) ? gr : 0;        // clamp; stores are guarded
      a[rt] = *reinterpret_cast<const bf16x8*>(Au + (size_t)gra * 128 + s * 32 + lk * 8);
    }
#pragma unroll
    for (int ct = 0; ct < CT; ++ct) {
      bf16x8 bhi = *reinterpret_cast<const bf16x8*>(&Wt[0][ct * 16 + lrow][s * 32 + lk * 8]);
      bf16x8 blo = *reinterpret_cast<const bf16x8*>(&Wt[1][ct * 16 + lrow][s * 32 + lk * 8]);
      acc[0][ct] = __builtin_amdgcn_mfma_f32_16x16x32_bf16(a[0], bhi, acc[0][ct], 0, 0, 0);
      acc[1][ct] = __builtin_amdgcn_mfma_f32_16x16x32_bf16(a[1], bhi, acc[1][ct], 0, 0, 0);
      acc[0][ct] = __builtin_amdgcn_mfma_f32_16x16x32_bf16(a[0], blo, acc[0][ct], 0, 0, 0);
      acc[1][ct] = __builtin_amdgcn_mfma_f32_16x16x32_bf16(a[1], blo, acc[1][ct], 0, 0, 0);
    }
  }

  // store: C/D mapping col=lane&15, row=(lane>>4)*4+reg
#pragma unroll
  for (int rt = 0; rt < 2; ++rt)
#pragma unroll
    for (int ct = 0; ct < CT; ++ct)
#pragma unroll
      for (int r = 0; r < 4; ++r) {
        int gr = rowbase + rt * 16 + lk * 4 + r;
        if (gr >= nrows) continue;
        int col = ct * 16 + lrow;
        float v = acc[rt][ct][r];
        if constexpr (OUT_BF16) {
          ((uint16_t*)Cout)[(size_t)gr * BN + col] = (uint16_t)f2bf(v);
        } else {
          ((float*)Cout)[(size_t)gr * BN + col] = v + bias[col];
        }
      }
}

// ---------------- aggregation: one wave64 per node, bf16 rows, 4-way unroll ----------------
__global__ __launch_bounds__(256)
void agg_kernel(const uint32_t* __restrict__ hwb, float* __restrict__ h,
                uint32_t* __restrict__ hb, const float* __restrict__ bias,
                const int* __restrict__ off, const uint2* __restrict__ csr,
                const float* __restrict__ dis, int relu, int n) {
  int wid = (blockIdx.x * blockDim.x + threadIdx.x) >> 6;
  int lane = threadIdx.x & 63;
  if (wid >= n) return;
  int v = wid;
  float dv = dis[v];
  float sw = dv * dv;
  uint32_t hvw = hwb[(size_t)v * 64 + lane];
  float2* hr = (float2*)(h + (size_t)v * 128);
  float2 res = hr[lane];
  float2 bb = ((const float2*)bias)[lane];
  float accx = fmaf(sw, bf_lo(hvw), bb.x + res.x);
  float accy = fmaf(sw, bf_hi(hvw), bb.y + res.y);
  int s0 = off[v], s1 = off[v + 1];
  int i = s0;
  for (; i + 3 < s1; i += 4) {
    uint2 c0 = csr[i], c1 = csr[i + 1], c2 = csr[i + 2], c3 = csr[i + 3];
    uint32_t r0 = hwb[(size_t)c0.x * 64 + lane];
    uint32_t r1 = hwb[(size_t)c1.x * 64 + lane];
    uint32_t r2 = hwb[(size_t)c2.x * 64 + lane];
    uint32_t r3 = hwb[(size_t)c3.x * 64 + lane];
    float w0 = __uint_as_float(c0.y), w1 = __uint_as_float(c1.y);
    float w2 = __uint_as_float(c2.y), w3 = __uint_as_float(c3.y);
    accx = fmaf(w0, bf_lo(r0), accx); accy = fmaf(w0, bf_hi(r0), accy);
    accx = fmaf(w1, bf_lo(r1), accx); accy = fmaf(w1, bf_hi(r1), accy);
    accx = fmaf(w2, bf_lo(r2), accx); accy = fmaf(w2, bf_hi(r2), accy);
    accx = fmaf(w3, bf_lo(r3), accx); accy = fmaf(w3, bf_hi(r3), accy);
  }
  for (; i < s1; ++i) {
    uint2 c = csr[i];
    uint32_t r = hwb[(size_t)c.x * 64 + lane];
    float w = __uint_as_float(c.y);
    accx = fmaf(w, bf_lo(r), accx); accy = fmaf(w, bf_hi(r), accy);
  }
  if (relu) { accx = fmaxf(accx, 0.f); accy = fmaxf(accy, 0.f); }
  hr[lane] = make_float2(accx, accy);
  hb[(size_t)v * 64 + lane] = pack2(accx, accy);
}

// ---------------- dropout (bit-exact JAX threefry) ----------------
__global__ void dropout_part_kernel(float* __restrict__ out, int total, int mode) {
  int i = blockIdx.x * blockDim.x + threadIdx.x;
  if (i >= total) return;
  uint32_t x0 = 0u, x1 = (uint32_t)i;   // counter = (hi,lo) of u64 flat index
  threefry2x32(0u, 42u, x0, x1);
  uint32_t bits = (mode == 1) ? x0 : ((mode == 3) ? (x0 ^ x1) : x1);
  float u = __uint_as_float((bits >> 9) | 0x3F800000u) - 1.0f;
  float v = out[i];
  out[i] = (u < 0.8f) ? (v / 0.8f) : 0.0f;
}

// ---------------- launch ----------------
extern "C" void kernel_launch(void* const* d_in, const int* in_sizes, int n_in,
                              void* d_out, int out_size, void* d_ws, size_t ws_size,
                              hipStream_t stream) {
  const float* x     = (const float*)d_in[0];
  const float* query = (const float*)d_in[1];
  const int*   batch = (const int*)d_in[2];
  const int*   eidx  = (const int*)d_in[3];
  const float* W[4]  = {(const float*)d_in[4], (const float*)d_in[6],
                        (const float*)d_in[8], (const float*)d_in[10]};
  const float* bv[4] = {(const float*)d_in[5], (const float*)d_in[7],
                        (const float*)d_in[9], (const float*)d_in[11]};
  const float* Wc = (const float*)d_in[12];
  const float* bc = (const float*)d_in[13];
  float* out = (float*)d_out;

  const int n = in_sizes[2];       // 100000
  const int e = in_sizes[3] / 2;   // 1600000
  const int* fs = eidx;            // edge_index[0] = sources
  const int* fd = eidx + e;        // edge_index[1] = targets (aggregation index)

  char* p = (char*)d_ws;
  auto carve = [&](size_t bytes) -> void* {
    void* r = (void*)p;
    p += (bytes + 255) & ~(size_t)255;
    return r;
  };
  const int nscan = (n + 255) / 256;           // 391 (<= 512 for scanB)
  int*      cnt     = (int*)carve((size_t)n * 4);
  int*      cursor  = (int*)carve((size_t)n * 4);
  int*      off     = (int*)carve((size_t)(n + 1) * 4);
  int*      bsum    = (int*)carve((size_t)nscan * 4);
  int*      boff    = (int*)carve((size_t)nscan * 4);
  float*    dis     = (float*)carve((size_t)n * 4);
  uint2*    csr     = (uint2*)carve((size_t)e * 8);         // interleaved {src, w}
  float*    h       = (float*)carve((size_t)n * 128 * 4);   // fp32 residual
  uint32_t* hb      = (uint32_t*)carve((size_t)n * 64 * 4); // bf16 h (GEMM input)
  uint32_t* hwb     = (uint32_t*)carve((size_t)n * 64 * 4); // bf16 h@W (gather src)

  const int eb = (e + 255) / 256;

  init_kernel<<<nscan, 256, 0, stream>>>(cnt, cursor, n);
  count_kernel<<<eb, 256, 0, stream>>>(fd, cnt, e);
  scanA_kernel<<<nscan, 256, 0, stream>>>(cnt, off, bsum, n);
  scanB_kernel<<<1, 512, 0, stream>>>(bsum, boff, nscan, off, n);
  scanC_kernel<<<nscan, 256, 0, stream>>>(off, boff, cnt, dis, n);
  fill_kernel<<<eb, 256, 0, stream>>>(fs, fd, off, cursor, dis, csr, e);
  h0_kernel<<<(n * 64 + 255) / 256, 256, 0, stream>>>(x, query, batch, h, hb, n);

  const int gblk = (n + 127) / 128;
  for (int l = 0; l < 4; ++l) {
    mfma_gemm_kernel<128, 1><<<gblk, 256, 0, stream>>>(hb, W[l], nullptr, hwb, n);
    agg_kernel<<<(n + 3) / 4, 256, 0, stream>>>(hwb, h, hb, bv[l], off, csr,
                                                dis, (l < 3) ? 1 : 0, n);
  }
  mfma_gemm_kernel<64, 0><<<gblk, 256, 0, stream>>>(hb, Wc, bc, out, n);

  const int total = n * 64;
  dropout_part_kernel<<<(total + 255) / 256, 256, 0, stream>>>(out, total,
                                                               DROPOUT_VARIANT);
}